// Round 5
// baseline (70.003 us; speedup 1.0000x reference)
//
#include <hip/hip_runtime.h>
#include <math.h>

#define IMG_W 112
#define HW    12544          // 112*112
#define CI    8
#define CO    16
#define NP2   36             // patch-position pairs (72 p's / 2)
#define EPS   1e-6f

typedef __attribute__((ext_vector_type(8))) short short8;   // 8 bf16 = 4 VGPRs
typedef __attribute__((ext_vector_type(16))) float f32x16;  // 32x32 MFMA C/D

static __device__ inline short f2bf(float f) {  // RNE float->bf16 bits
  unsigned u = __float_as_uint(f);
  return (short)((u + 0x7FFFu + ((u >> 16) & 1u)) >> 16);
}

static constexpr int DQ[9] = {-113, -112, -111, -1, 0, 1, 111, 112, 113};

// Round 13: single launch -- fold the A-fragment pack into the main kernel.
//   r4 decomposition: 67.4us = 40.5 fill (unconditional, 83%-of-peak) +
//   ~21.3 fixed harness dispatches + ~5.6us pack+mfma. The pack kernel's
//   launch + dependency bubble (~2-4us) is the biggest addressable piece.
//   Here each block stages all 36 p-pairs' A-fragments into LDS (36,864B,
//   identical pack body: 512 thr x 4.5 frags, wp 36KB L2-hot) behind one
//   barrier; the hot loop reads ds_read_b128 (per-wave 1024B contiguous =
//   2-lanes/bank pairing, free). The partial-combine buffer OVERLAYS the
//   fragment buffer (dead after the main loop; r0-verified pattern), so LDS
//   stays 36,864B. Geometry unchanged from r4: 784 blocks x 512 thr,
//   8 waves = 2 px-groups x 4 p-quarters of 9 MFMAs.
__global__ __launch_bounds__(512, 6) void coda_mfma(
    const float* __restrict__ in, const float* __restrict__ wp,
    const float* __restrict__ bp, float* __restrict__ out)
{
  __shared__ short sA[NP2 * 64 * 8];              // 36864B; overlaid by partials

  const int tid = threadIdx.x;
  const int b   = blockIdx.x / 196;               // 196 blocks (64 px) per image
  const int r0  = (blockIdx.x - b * 196) * 64;    // first flat pixel of block
  const float* __restrict__ inb = in + b * CI * HW;

  // ---- stage A-fragments: [p2][lane][8 bf16], row o' = p2*32 + (lane&31) ----
  for (int idx = tid; idx < NP2 * 64; idx += 512) {
    const int p2 = idx >> 6, l = idx & 63, ah = l >> 5, m = l & 31;
    const int row = p2 * 32 + m;                  // o' = p*16 + co
    short8 v = {0, 0, 0, 0, 0, 0, 0, 0};
    if (ah == 0) {                                // K 0..7: channel weights
      const float* wr = wp + row * CI;
#pragma unroll
      for (int j = 0; j < 8; ++j) v[j] = f2bf(wr[j]);
    } else {                                      // K 8..15: bias at K=8
      v[0] = f2bf(bp[row]);
    }
    *(short8*)&sA[idx * 8] = v;
  }

  const int wave = tid >> 6;
  const int lane = tid & 63;
  const int g    = wave & 1;                      // pixel group (32 px)
  const int qh   = wave >> 1;                     // p-quarter: pairs [qh*9, qh*9+9)
  const int ln   = lane & 31;                     // pixel slot = D col
  const int hi   = lane >> 5;                     // K-group / D row-half
  const int px   = r0 + g * 32 + ln;
  const int hrow = px / IMG_W;
  const int wcol = px - hrow * IMG_W;

  // border masks per q = kh*3+kw (independent of staging -> before barrier)
  float vm[9];
#pragma unroll
  for (int q = 0; q < 9; ++q) {
    const int kh = q / 3, kw = q % 3;
    const bool ok = ((unsigned)(hrow + kh - 1) < 112u) &&
                    ((unsigned)(wcol + kw - 1) < 112u);
    vm[q] = ok ? 1.f : 0.f;
  }

  // B fragment: hi=0 lanes = x[c=0..7, px] bf16; hi=1 lanes = 1.0 at K=8
  short8 bf;
#pragma unroll
  for (int j = 0; j < 8; ++j) {
    const short bv = f2bf(inb[j * HW + px]);
    bf[j] = (hi == 0) ? bv : ((j == 0) ? (short)0x3F80 : (short)0);
  }

  __syncthreads();                                // A-fragments ready

  float acc[8] = {0.f, 0.f, 0.f, 0.f, 0.f, 0.f, 0.f, 0.f};
  float n2[8]  = {0.f, 0.f, 0.f, 0.f, 0.f, 0.f, 0.f, 0.f};

  // per-lane A-fragment base within LDS: ((qh*9 + t)*64 + lane) * 8 shorts
  const short* __restrict__ abase = &sA[(qh * 9 * 64 + lane) * 8];

#pragma unroll
  for (int t = 0; t < 9; ++t) {
    // pair p2 = qh*9 + t; p0 = 18*qh + 2t. 18*qh % 9 == 0 -> q literal in t:
    const int q0_ = (2 * t) % 9;                  // compile-time
    const int q1_ = (2 * t + 1) % 9;              // compile-time
    const int c0_ = 2 * qh + (2 * t) / 9;         // runtime qh, addr-only
    const int c1_ = 2 * qh + (2 * t + 1) / 9;

    const short8 af = *(const short8*)(abase + t * 512);  // b128, conflict-free

    int i0 = px + DQ[q0_]; i0 = i0 < 0 ? 0 : (i0 > HW - 1 ? HW - 1 : i0);
    int i1 = px + DQ[q1_]; i1 = i1 < 0 ? 0 : (i1 > HW - 1 ? HW - 1 : i1);
    const float pv0 = vm[q0_] * inb[c0_ * HW + i0];
    const float pv1 = vm[q1_] * inb[c1_ * HW + i1];

    const f32x16 zc = {0.f, 0.f, 0.f, 0.f, 0.f, 0.f, 0.f, 0.f,
                       0.f, 0.f, 0.f, 0.f, 0.f, 0.f, 0.f, 0.f};
    const f32x16 d =
        __builtin_amdgcn_mfma_f32_32x32x16_bf16(af, bf, zc, 0, 0, 0);
#pragma unroll
    for (int i = 0; i < 16; ++i) {                // i>>3 = p_local, i&7 = slot
      const float pv = (i < 8) ? pv0 : pv1;
      acc[i & 7] = fmaf(pv, d[i], acc[i & 7]);
      n2[i & 7]  = fmaf(d[i], d[i], n2[i & 7]);
    }
  }

  // ---- combine 4 p-quarters via LDS overlay (sA dead), quarter 0 stores ----
  __syncthreads();                                // all ds_reads of sA done
  float* __restrict__ sPart = (float*)sA;         // 6*1024 floats = 24576B
  if (qh != 0) {
    const int slot = ((qh - 1) * 2 + g) * 1024;   // 16 rows of 64 per (qh,g)
#pragma unroll
    for (int j = 0; j < 8; ++j) {
      sPart[slot + j * 64 + lane]       = acc[j]; // lane-stride-1: no conflicts
      sPart[slot + (8 + j) * 64 + lane] = n2[j];
    }
  }
  __syncthreads();
  if (qh == 0) {
    float* __restrict__ ob = out + (long)b * CO * HW + px;
#pragma unroll
    for (int j = 0; j < 8; ++j) {
      float a2 = acc[j];
      float s2 = n2[j];
#pragma unroll
      for (int u = 0; u < 3; ++u) {
        a2 += sPart[(u * 2 + g) * 1024 + j * 64 + lane];
        s2 += sPart[(u * 2 + g) * 1024 + (8 + j) * 64 + lane];
      }
      const int co = (j & 3) + 8 * (j >> 2) + 4 * hi;
      ob[(long)co * HW] = a2 / (sqrtf(s2) + EPS);
    }
  }
}

extern "C" void kernel_launch(void* const* d_in, const int* in_sizes, int n_in,
                              void* d_out, int out_size, void* d_ws, size_t ws_size,
                              hipStream_t stream) {
  const float* in = (const float*)d_in[0];
  const float* wp = (const float*)d_in[1];
  const float* bp = (const float*)d_in[2];
  float* out = (float*)d_out;
  (void)d_ws; (void)ws_size;

  // single launch: 50176 px / 64 = 784 blocks of 8 waves
  coda_mfma<<<dim3(784), dim3(512), 0, stream>>>(in, wp, bp, out);
}

// Round 6
// 67.407 us; speedup vs baseline: 1.0385x; 1.0385x over previous
//
#include <hip/hip_runtime.h>
#include <math.h>

#define IMG_W 112
#define HW    12544          // 112*112
#define CI    8
#define CO    16
#define NP2   36             // patch-position pairs (72 p's / 2)
#define EPS   1e-6f

typedef __attribute__((ext_vector_type(8))) short short8;   // 8 bf16 = 4 VGPRs
typedef __attribute__((ext_vector_type(16))) float f32x16;  // 32x32 MFMA C/D

static __device__ inline short f2bf(float f) {  // RNE float->bf16 bits
  unsigned u = __float_as_uint(f);
  return (short)((u + 0x7FFFu + ((u >> 16) & 1u)) >> 16);
}

static constexpr int DQ[9] = {-113, -112, -111, -1, 0, 1, 111, 112, 113};

// Round 14: REVERT to the round-4 (r12) kernel -- the measured optimum.
//   r5's fold-in (per-block LDS pack) regressed 67.4 -> 70.0: 784 blocks
//   each re-doing the pack (~70 VALU/thread + extra barrier on the critical
//   path) costs more than the 9-block pack kernel + launch bubble it removed.
//   Design-space summary (all harness-verified):
//     r0 16x16+staged+6272w: 72.2 | r2 32x32+ws+3136w: 72.6 | r3 stageless:
//     173.8 | r4 32x32+ws+6272w: 67.4 | r5 32x32+LDS-fold: 70.0
//   67.4 = 40.5 fill (unconditional, 83% HBM peak) + ~21.3 fixed dispatches
//   + ~5.6us kernel. Both structural neighbors of r4 measured worse.
__global__ __launch_bounds__(256) void coda_pack(
    const float* __restrict__ wp, const float* __restrict__ bp,
    short* __restrict__ wpk)
{
  const int t = blockIdx.x * 256 + threadIdx.x;   // 0..2303 = NP2*64
  if (t >= NP2 * 64) return;
  const int p2 = t >> 6, l = t & 63, ah = l >> 5, m = l & 31;
  const int row = p2 * 32 + m;                    // o' = p*16 + co
  short8 v = {0, 0, 0, 0, 0, 0, 0, 0};
  if (ah == 0) {                                  // K 0..7: channel weights
    const float* wr = wp + row * CI;
#pragma unroll
    for (int j = 0; j < 8; ++j) v[j] = f2bf(wr[j]);
  } else {                                        // K 8..15: bias at K=8
    v[0] = f2bf(bp[row]);
  }
  *(short8*)&wpk[t * 8] = v;
}

__global__ __launch_bounds__(512, 6) void coda_mfma(
    const float* __restrict__ in, const short* __restrict__ wpk,
    float* __restrict__ out)
{
  __shared__ float sPart[6 * 1024];               // 24576B: quarters 1-3 partials

  const int tid = threadIdx.x;
  const int b   = blockIdx.x / 196;               // 196 blocks (64 px) per image
  const int r0  = (blockIdx.x - b * 196) * 64;    // first flat pixel of block
  const float* __restrict__ inb = in + b * CI * HW;

  const int wave = tid >> 6;
  const int lane = tid & 63;
  const int g    = wave & 1;                      // pixel group (32 px)
  const int qh   = wave >> 1;                     // p-quarter: pairs [qh*9, qh*9+9)
  const int ln   = lane & 31;                     // pixel slot = D col
  const int hi   = lane >> 5;                     // K-group / D row-half
  const int px   = r0 + g * 32 + ln;
  const int hrow = px / IMG_W;
  const int wcol = px - hrow * IMG_W;

  // border masks per q = kh*3+kw
  float vm[9];
#pragma unroll
  for (int q = 0; q < 9; ++q) {
    const int kh = q / 3, kw = q % 3;
    const bool ok = ((unsigned)(hrow + kh - 1) < 112u) &&
                    ((unsigned)(wcol + kw - 1) < 112u);
    vm[q] = ok ? 1.f : 0.f;
  }

  // B fragment: hi=0 lanes = x[c=0..7, px] bf16; hi=1 lanes = 1.0 at K=8
  short8 bf;
#pragma unroll
  for (int j = 0; j < 8; ++j) {
    const short bv = f2bf(inb[j * HW + px]);
    bf[j] = (hi == 0) ? bv : ((j == 0) ? (short)0x3F80 : (short)0);
  }

  float acc[8] = {0.f, 0.f, 0.f, 0.f, 0.f, 0.f, 0.f, 0.f};
  float n2[8]  = {0.f, 0.f, 0.f, 0.f, 0.f, 0.f, 0.f, 0.f};

  // per-lane A-fragment base: ((qh*9 + t)*64 + lane) * 8 shorts
  const short* __restrict__ wbase = wpk + (qh * 9 * 64 + lane) * 8;

#pragma unroll
  for (int t = 0; t < 9; ++t) {
    // pair p2 = qh*9 + t; p0 = 18*qh + 2t. 18*qh % 9 == 0 -> q literal in t:
    const int q0_ = (2 * t) % 9;                  // compile-time
    const int q1_ = (2 * t + 1) % 9;              // compile-time
    const int c0_ = 2 * qh + (2 * t) / 9;         // runtime qh, addr-only
    const int c1_ = 2 * qh + (2 * t + 1) / 9;

    const short8 af = *(const short8*)(wbase + t * 512);

    int i0 = px + DQ[q0_]; i0 = i0 < 0 ? 0 : (i0 > HW - 1 ? HW - 1 : i0);
    int i1 = px + DQ[q1_]; i1 = i1 < 0 ? 0 : (i1 > HW - 1 ? HW - 1 : i1);
    const float pv0 = vm[q0_] * inb[c0_ * HW + i0];
    const float pv1 = vm[q1_] * inb[c1_ * HW + i1];

    const f32x16 zc = {0.f, 0.f, 0.f, 0.f, 0.f, 0.f, 0.f, 0.f,
                       0.f, 0.f, 0.f, 0.f, 0.f, 0.f, 0.f, 0.f};
    const f32x16 d =
        __builtin_amdgcn_mfma_f32_32x32x16_bf16(af, bf, zc, 0, 0, 0);
#pragma unroll
    for (int i = 0; i < 16; ++i) {                // i>>3 = p_local, i&7 = slot
      const float pv = (i < 8) ? pv0 : pv1;
      acc[i & 7] = fmaf(pv, d[i], acc[i & 7]);
      n2[i & 7]  = fmaf(d[i], d[i], n2[i & 7]);
    }
  }

  // ---- combine 4 p-quarters via LDS, quarter 0 stores ----
  if (qh != 0) {
    const int slot = ((qh - 1) * 2 + g) * 1024;   // 16 rows of 64 per (qh,g)
#pragma unroll
    for (int j = 0; j < 8; ++j) {
      sPart[slot + j * 64 + lane]       = acc[j]; // lane-stride-1: no conflicts
      sPart[slot + (8 + j) * 64 + lane] = n2[j];
    }
  }
  __syncthreads();
  if (qh == 0) {
    float* __restrict__ ob = out + (long)b * CO * HW + px;
#pragma unroll
    for (int j = 0; j < 8; ++j) {
      float a2 = acc[j];
      float s2 = n2[j];
#pragma unroll
      for (int u = 0; u < 3; ++u) {
        a2 += sPart[(u * 2 + g) * 1024 + j * 64 + lane];
        s2 += sPart[(u * 2 + g) * 1024 + (8 + j) * 64 + lane];
      }
      const int co = (j & 3) + 8 * (j >> 2) + 4 * hi;
      ob[(long)co * HW] = a2 / (sqrtf(s2) + EPS);
    }
  }
}

extern "C" void kernel_launch(void* const* d_in, const int* in_sizes, int n_in,
                              void* d_out, int out_size, void* d_ws, size_t ws_size,
                              hipStream_t stream) {
  const float* in = (const float*)d_in[0];
  const float* wp = (const float*)d_in[1];
  const float* bp = (const float*)d_in[2];
  float* out = (float*)d_out;
  short* wpk = (short*)d_ws;                      // 36*64*8 shorts = 36,864 B

  // pack A-fragments once (9 blocks x 256 = 2304 threads = NP2*64)
  coda_pack<<<dim3(9), dim3(256), 0, stream>>>(wp, bp, wpk);
  // 50176 px / 64 per block = 784 blocks of 8 waves (2 px-groups x 4 p-quarters)
  coda_mfma<<<dim3(784), dim3(512), 0, stream>>>(in, wpk, out);
}